// Round 3
// baseline (608.174 us; speedup 1.0000x reference)
//
#include <hip/hip_runtime.h>

// OverlapWindowMHA2d on MI355X (gfx950) — R4.
// prep (w->bf16) ; merged fused qkv+MFMA-attention ; head GEMM.
// R4 theory: both GEMMs were latency-serialized on operand loads (R3's spill
// corrupted the occupancy experiment). Fix = ILP, not TLP:
//   - qkv_attn: 512 thr, __launch_bounds__(512,2) -> 256 unified regs/lane,
//     spill-free; register double-buffer prefetch of W fragments (afr[2][9])
//     and x fragments (bfr[2][2]) one K-chunk ahead; no barrier in K-loop.
//   - head_gemm: __launch_bounds__(256,3); register dbuf prefetch (a[2][3],
//     bb[2][4]) one K-chunk ahead; no LDS, no barriers.
// Workspace layout (~101.3 MB):
//   [0)            o_cat bf16 [b][win(1024)][n(16)][c(384)]   = 100,663,296 B
//   [+100663296)   w_qkv1 bf16 (576x192)
//   [+100884480)   w_qkv2 bf16 (576x192)
//   [+101105664)   w_head bf16 (192x384)

typedef unsigned short u16;
using bf16x8 = __attribute__((ext_vector_type(8))) short;
using f32x4  = __attribute__((ext_vector_type(4))) float;
using u16x8  = __attribute__((ext_vector_type(8))) unsigned short;
using u16x4  = __attribute__((ext_vector_type(4))) unsigned short;

#define CIN   192
#define CQKV  576
#define NW2   33

__device__ __forceinline__ float bf2f(u16 u) {
    unsigned int x = ((unsigned int)u) << 16;
    float f; __builtin_memcpy(&f, &x, 4); return f;
}
__device__ __forceinline__ u16 f2bf(float f) {
    unsigned int x; __builtin_memcpy(&x, &f, 4);
    return (u16)((x + 0x7FFFu + ((x >> 16) & 1u)) >> 16);
}
// x-tile LDS column swizzle: spreads banks for the [tok][c] scalar writes while
// keeping 8-element (16B) k-blocks contiguous for b128 fragment reads.
__device__ __forceinline__ int xcol(int c, int tok) {
    int blk = (c >> 3) ^ ((tok ^ (tok >> 4)) & 7);     // blk stays < 24
    return blk * 8 + (c & 7);
}

__global__ void prep_conv(const float* __restrict__ w1, const float* __restrict__ w2,
                          const float* __restrict__ wh,
                          u16* __restrict__ w1b, u16* __restrict__ w2b, u16* __restrict__ whb) {
    int i = blockIdx.x * 256 + threadIdx.x;            // 294912 total
    if (i < 110592)        w1b[i] = f2bf(w1[i]);
    else if (i < 221184)   w2b[i - 110592] = f2bf(w2[i - 110592]);
    else                   whb[i - 221184] = f2bf(wh[i - 221184]);
}

// ---------------------------------------------------------------------------
// Fused QKV (MFMA, M=576 N=64 K=192) + MFMA attention. 4 windows per block,
// 512 threads (8 waves: wave_m = wave>>1 co-stripe of 144, wave_n = wave&1
// token half of 32). 256 regs/lane (launch_bounds 512,2) -> 1 block/CU.
// K-loop: register-dbuf prefetch of A (global, L2-hot) and B (LDS) fragments.
// 3 __syncthreads per block: post-x-load, post-MFMA, post-restage.
// ---------------------------------------------------------------------------
__global__ __launch_bounds__(512, 2) void qkv_attn(const float* __restrict__ x,
                                                   const u16* __restrict__ w1b,
                                                   const float* __restrict__ b1,
                                                   const u16* __restrict__ w2b,
                                                   const float* __restrict__ b2,
                                                   u16* __restrict__ ocat) {
    // Phase1: xl [0,25600) pitch 200 u16
    // Phase2: qk [0,50176) pitch 392 u16 ; vT [50176,74752) [24][32][16] ;
    //         pl [74752,80896) [8][16][24]
    __shared__ __align__(16) char smem[80896];
    u16* xl = (u16*)smem;
    u16* qk = (u16*)smem;
    u16* vt = (u16*)(smem + 50176);
    u16* pl = (u16*)(smem + 74752);

    const int tid  = threadIdx.x;
    const int wave = tid >> 6, lane = tid & 63;
    const int lo16 = lane & 15, quad = lane >> 4;

    // XCD-bijective swizzle: 4424 blocks = 8 XCDs * 553.
    const int swz = (blockIdx.x & 7) * 553 + (blockIdx.x >> 3);
    const bool br0 = (swz < 2048);

    int b, wy, g;
    const u16* wb; const float* bias;
    if (br0) {                           // 8 * 32 * 8 = 2048
        b = swz >> 8; int rem = swz & 255;
        wy = rem >> 3; g = rem & 7;
        wb = w1b; bias = b1;
    } else {                             // 8 * 33 * 9 = 2376
        int bi = swz - 2048;
        b = bi / 297; int rem = bi % 297;
        wy = rem / 9; g = rem % 9;
        wb = w2b; bias = b2;
    }
    const int hbase = wy * 4, wbase = g * 16;

    // --- x tile: 4 windows x 16 tok x 192 ch -> LDS bf16 ---
    if (br0) {
#pragma unroll
        for (int it = 0; it < 6; ++it) {
            int i = it * 512 + tid;          // c(192) x y(4) x xc(4)
            int c = i >> 4, y = (i >> 2) & 3, xc = i & 3;
            const float4 v = *reinterpret_cast<const float4*>(
                &x[(((size_t)b * CIN + c) * 128 + hbase + y) * 128 + wbase + xc * 4]);
            int t0 = xc * 16 + y * 4;
            xl[(t0 + 0) * 200 + xcol(c, t0 + 0)] = f2bf(v.x);
            xl[(t0 + 1) * 200 + xcol(c, t0 + 1)] = f2bf(v.y);
            xl[(t0 + 2) * 200 + xcol(c, t0 + 2)] = f2bf(v.z);
            xl[(t0 + 3) * 200 + xcol(c, t0 + 3)] = f2bf(v.w);
        }
    } else {
#pragma unroll
        for (int it = 0; it < 6; ++it) {
            int i = it * 512 + tid;
            int c = i >> 4, y = (i >> 2) & 3, xc = i & 3;
            float e0, e1, e2, e3;
            int h = hbase + y - 2;
            int w0 = wbase + xc * 4 - 2;
            bool hok = (unsigned)h < 128u;
            const float* row = &x[(((size_t)b * CIN + c) * 128 + h) * 128];
            if (hok && w0 >= 0 && w0 + 3 < 128) {
                float2 p0 = *reinterpret_cast<const float2*>(&row[w0]);
                float2 p1 = *reinterpret_cast<const float2*>(&row[w0 + 2]);
                e0 = p0.x; e1 = p0.y; e2 = p1.x; e3 = p1.y;
            } else {
                e0 = (hok && w0 >= 0 && w0 < 128)         ? row[w0]     : 0.f;
                e1 = (hok && w0+1 >= 0 && w0+1 < 128)     ? row[w0 + 1] : 0.f;
                e2 = (hok && w0+2 >= 0 && w0+2 < 128)     ? row[w0 + 2] : 0.f;
                e3 = (hok && w0+3 >= 0 && w0+3 < 128)     ? row[w0 + 3] : 0.f;
            }
            int t0 = xc * 16 + y * 4;
            xl[(t0 + 0) * 200 + xcol(c, t0 + 0)] = f2bf(e0);
            xl[(t0 + 1) * 200 + xcol(c, t0 + 1)] = f2bf(e1);
            xl[(t0 + 2) * 200 + xcol(c, t0 + 2)] = f2bf(e2);
            xl[(t0 + 3) * 200 + xcol(c, t0 + 3)] = f2bf(e3);
        }
    }
    __syncthreads();

    // --- MFMA: qkv[co 576][tok 64], K=192 in 6 chunks; A direct from global,
    //     register-dbuf one chunk ahead (no barrier inside loop). ---
    const int wm = wave >> 1;            // co stripe (144 rows)
    const int wn = wave & 1;             // token half (32 tokens)

    f32x4 acc[9][2];
#pragma unroll
    for (int mt = 0; mt < 9; ++mt)
#pragma unroll
        for (int nt = 0; nt < 2; ++nt) acc[mt][nt] = f32x4{0.f, 0.f, 0.f, 0.f};

    const u16* wrow = wb + (size_t)(wm * 144 + lo16) * 192 + quad * 8;
    const int tokA = wn * 32 + lo16;           // nt = 0
    const int tokB = wn * 32 + 16 + lo16;      // nt = 1
    const int swA = ((tokA ^ (tokA >> 4)) & 7);
    const int swB = ((tokB ^ (tokB >> 4)) & 7);

    bf16x8 afr[2][9];
    bf16x8 bfr[2][2];
    // prologue: chunk s=0
#pragma unroll
    for (int mt = 0; mt < 9; ++mt)
        afr[0][mt] = *reinterpret_cast<const bf16x8*>(&wrow[mt * 3072]);
    bfr[0][0] = *reinterpret_cast<const bf16x8*>(&xl[tokA * 200 + ((quad ^ swA) << 3)]);
    bfr[0][1] = *reinterpret_cast<const bf16x8*>(&xl[tokB * 200 + ((quad ^ swB) << 3)]);

#pragma unroll
    for (int s = 0; s < 6; ++s) {
        const int cs = s & 1;
        if (s < 5) {
            const int kb = (s + 1) * 4 + quad;
#pragma unroll
            for (int mt = 0; mt < 9; ++mt)
                afr[cs ^ 1][mt] = *reinterpret_cast<const bf16x8*>(
                    &wrow[mt * 3072 + (s + 1) * 32]);
            bfr[cs ^ 1][0] = *reinterpret_cast<const bf16x8*>(
                &xl[tokA * 200 + ((kb ^ swA) << 3)]);
            bfr[cs ^ 1][1] = *reinterpret_cast<const bf16x8*>(
                &xl[tokB * 200 + ((kb ^ swB) << 3)]);
        }
#pragma unroll
        for (int mt = 0; mt < 9; ++mt) {
            acc[mt][0] = __builtin_amdgcn_mfma_f32_16x16x32_bf16(afr[cs][mt], bfr[cs][0], acc[mt][0], 0, 0, 0);
            acc[mt][1] = __builtin_amdgcn_mfma_f32_16x16x32_bf16(afr[cs][mt], bfr[cs][1], acc[mt][1], 0, 0, 0);
        }
    }
    __syncthreads();     // all xl reads done before qk overwrites the region

    // --- restage: Q (scaled) / K -> qk[tok][392] ; V -> vT transposed ---
    const float scale = 0.17677669529663687f;     // 1/sqrt(32)
#pragma unroll
    for (int mt = 0; mt < 9; ++mt) {
        int co0 = wm * 144 + mt * 16 + quad * 4;
        const float4 bv = *reinterpret_cast<const float4*>(&bias[co0]);
#pragma unroll
        for (int nt = 0; nt < 2; ++nt) {
            int tok = wn * 32 + nt * 16 + lo16;
            float v0 = acc[mt][nt][0] + bv.x, v1 = acc[mt][nt][1] + bv.y;
            float v2 = acc[mt][nt][2] + bv.z, v3 = acc[mt][nt][3] + bv.w;
            if (co0 < 192) { v0 *= scale; v1 *= scale; v2 *= scale; v3 *= scale; }
            if (co0 < 384) {
                u16x4 pk = {f2bf(v0), f2bf(v1), f2bf(v2), f2bf(v3)};
                *reinterpret_cast<u16x4*>(&qk[tok * 392 + co0]) = pk;
            } else {
                int dh = co0 - 384;
                int head = dh >> 5, d0 = dh & 31;
                int win = tok >> 4, m = tok & 15;
                u16* vrow = &vt[((win * 6 + head) * 32 + d0) * 16 + m];
                vrow[0]  = f2bf(v0);
                vrow[16] = f2bf(v1);
                vrow[32] = f2bf(v2);
                vrow[48] = f2bf(v3);
            }
        }
    }
    __syncthreads();

    // --- attention: 2 waves per window, 3 heads each, all MFMA ---
    {
        const int win = wave >> 1;                 // 0..3
        const int h0  = (wave & 1) * 3;            // heads h0..h0+2
        const u16* qbase = qk + (size_t)(win * 16) * 392;
        const bf16x8 z8 = {};
        const f32x4 zc = {0.f, 0.f, 0.f, 0.f};
        // precompute store mapping (per lane token n = lo16)
        bool dov; size_t dst = 0;
        if (br0) {
            int wg = wy * 32 + g * 4 + win;
            dst = (((size_t)(b * 1024 + wg)) * 16 + lo16) * 384;
            dov = true;
        } else {
            int wx = g * 4 + win;
            int h = wy * 4 + (lo16 >> 2) - 2;
            int w = wx * 4 + (lo16 & 3) - 2;
            dov = (wx < NW2) && (unsigned)h < 128u && (unsigned)w < 128u;
            if (dov) {
                int wg = (h >> 2) * 32 + (w >> 2);
                int nn = (h & 3) * 4 + (w & 3);
                dst = (((size_t)(b * 1024 + wg)) * 16 + nn) * 384 + 192;
            }
        }
#pragma unroll
        for (int hh = 0; hh < 3; ++hh) {
            const int head = h0 + hh;
            bf16x8 kfr = *reinterpret_cast<const bf16x8*>(
                &qbase[lo16 * 392 + 192 + head * 32 + quad * 8]);
            bf16x8 qfr = *reinterpret_cast<const bf16x8*>(
                &qbase[lo16 * 392 + head * 32 + quad * 8]);
            f32x4 st = __builtin_amdgcn_mfma_f32_16x16x32_bf16(kfr, qfr, zc, 0, 0, 0);
            // softmax over m (rows: quad*4+r across quads)
            float mx = fmaxf(fmaxf(st[0], st[1]), fmaxf(st[2], st[3]));
            mx = fmaxf(mx, __shfl_xor(mx, 16));
            mx = fmaxf(mx, __shfl_xor(mx, 32));
            float p0 = __expf(st[0] - mx), p1 = __expf(st[1] - mx);
            float p2 = __expf(st[2] - mx), p3 = __expf(st[3] - mx);
            float sum = p0 + p1 + p2 + p3;
            sum += __shfl_xor(sum, 16);
            sum += __shfl_xor(sum, 32);
            float inv = 1.0f / sum;
            u16x4 pk = {f2bf(p0), f2bf(p1), f2bf(p2), f2bf(p3)};
            *reinterpret_cast<u16x4*>(&pl[(wave * 16 + lo16) * 24 + quad * 4]) = pk;
            bf16x8 pf = (quad < 2)
                ? *reinterpret_cast<const bf16x8*>(&pl[(wave * 16 + lo16) * 24 + quad * 8]) : z8;
            const u16* vbase = &vt[(win * 6 + head) * 32 * 16];
#pragma unroll
            for (int half = 0; half < 2; ++half) {
                bf16x8 av = (quad < 2)
                    ? *reinterpret_cast<const bf16x8*>(&vbase[(half * 16 + lo16) * 16 + quad * 8]) : z8;
                f32x4 o = __builtin_amdgcn_mfma_f32_16x16x32_bf16(av, pf, zc, 0, 0, 0);
                if (dov) {
                    u16x4 ok = {f2bf(o[0] * inv), f2bf(o[1] * inv),
                                f2bf(o[2] * inv), f2bf(o[3] * inv)};
                    *reinterpret_cast<u16x4*>(&ocat[dst + head * 32 + half * 16 + quad * 4]) = ok;
                }
            }
        }
    }
}

// ---------------------------------------------------------------------------
// head GEMM: out[b][co 192][h][w] = w_head(192x384) @ o_cat rows + bias.
// No LDS, no barriers. Register-dbuf prefetch of A (whb, L2-hot) and
// B (ocat, HBM/L3) fragments one K-chunk ahead.
// ---------------------------------------------------------------------------
__global__ __launch_bounds__(256, 3) void head_gemm(const u16* __restrict__ ocat,
                                                    const u16* __restrict__ whb,
                                                    const float* __restrict__ bh,
                                                    float* __restrict__ out) {
    const int tid = threadIdx.x;
    const int wave = tid >> 6, lane = tid & 63;
    const int lo16 = lane & 15, quad = lane >> 4;

    int bi = blockIdx.x;                    // 8 * 32 * 8 = 2048
    int b = bi >> 8; int rem = bi & 255;
    int wy = rem >> 3, g = rem & 7;
    const int wg0 = wy * 32 + g * 4;
    const size_t gbase = ((size_t)(b * 1024 + wg0) * 16) * 384;

    const int co_base = wave * 48;
    f32x4 acc[3][4];
#pragma unroll
    for (int mt = 0; mt < 3; ++mt)
#pragma unroll
        for (int nt = 0; nt < 4; ++nt) acc[mt][nt] = f32x4{0.f, 0.f, 0.f, 0.f};

    const u16* bbase = &ocat[gbase + (size_t)lo16 * 384 + quad * 8];
    const u16* abase = &whb[(size_t)(co_base + lo16) * 384 + quad * 8];

    bf16x8 a[2][3], bb[2][4];
    // prologue: chunk s=0
#pragma unroll
    for (int nt = 0; nt < 4; ++nt)
        bb[0][nt] = *reinterpret_cast<const bf16x8*>(&bbase[nt * 16 * 384]);
#pragma unroll
    for (int mt = 0; mt < 3; ++mt)
        a[0][mt] = *reinterpret_cast<const bf16x8*>(&abase[mt * 16 * 384]);

#pragma unroll
    for (int s = 0; s < 12; ++s) {
        const int cs = s & 1;
        if (s < 11) {
            const int k1 = (s + 1) * 32;
#pragma unroll
            for (int nt = 0; nt < 4; ++nt)
                bb[cs ^ 1][nt] = *reinterpret_cast<const bf16x8*>(&bbase[nt * 16 * 384 + k1]);
#pragma unroll
            for (int mt = 0; mt < 3; ++mt)
                a[cs ^ 1][mt] = *reinterpret_cast<const bf16x8*>(&abase[mt * 16 * 384 + k1]);
        }
#pragma unroll
        for (int mt = 0; mt < 3; ++mt)
#pragma unroll
            for (int nt = 0; nt < 4; ++nt)
                acc[mt][nt] = __builtin_amdgcn_mfma_f32_16x16x32_bf16(a[cs][mt], bb[cs][nt], acc[mt][nt], 0, 0, 0);
    }

    int h = wy * 4 + (lo16 >> 2);
#pragma unroll
    for (int mt = 0; mt < 3; ++mt) {
        int co0 = co_base + mt * 16 + quad * 4;
        const float4 bv = *reinterpret_cast<const float4*>(&bh[co0]);
#pragma unroll
        for (int r = 0; r < 4; ++r) {
            float bias = (r == 0) ? bv.x : (r == 1) ? bv.y : (r == 2) ? bv.z : bv.w;
#pragma unroll
            for (int nt = 0; nt < 4; ++nt) {
                int w = (g * 4 + nt) * 4 + (lo16 & 3);
                out[(((size_t)b * CIN + co0 + r) * 128 + h) * 128 + w] = acc[mt][nt][r] + bias;
            }
        }
    }
}

// ---------------------------------------------------------------------------
extern "C" void kernel_launch(void* const* d_in, const int* in_sizes, int n_in,
                              void* d_out, int out_size, void* d_ws, size_t ws_size,
                              hipStream_t stream) {
    const float* x  = (const float*)d_in[0];
    const float* w1 = (const float*)d_in[1];
    const float* b1 = (const float*)d_in[2];
    const float* w2 = (const float*)d_in[3];
    const float* b2 = (const float*)d_in[4];
    const float* wh = (const float*)d_in[5];
    const float* bh = (const float*)d_in[6];
    float* out = (float*)d_out;

    char* ws = (char*)d_ws;
    u16* ocat = (u16*)ws;
    u16* w1b  = (u16*)(ws + 100663296);
    u16* w2b  = (u16*)(ws + 100884480);
    u16* whb  = (u16*)(ws + 101105664);

    prep_conv<<<1152, 256, 0, stream>>>(w1, w2, wh, w1b, w2b, whb);
    qkv_attn<<<4424, 512, 0, stream>>>(x, w1b, b1, w2b, b2, ocat);
    head_gemm<<<2048, 256, 0, stream>>>(ocat, whb, bh, out);
}

// Round 4
// 537.018 us; speedup vs baseline: 1.1325x; 1.1325x over previous
//
#include <hip/hip_runtime.h>

// OverlapWindowMHA2d on MI355X (gfx950) — R5.
// prep (permute W to head-major, fold q-scale, bf16) ; fused qkv+attention with
// per-head waves and wave-private attention ; head GEMM (32-tok tiles).
//
// R5 structure (theory: kill the phase-2 LDS monolith + serial phase chain):
//   - qkv_attn: 384 thr = 6 waves; wave w owns head w's co-strip [w*96, w*96+96)
//     = q|k|v of head w (head-major W permutation done in prep). After the QKV
//     GEMM each wave holds Q,K,V of its head for all 4 windows in acc[6][4] —
//     attention is fully wave-private. LDS: xl 25.6K + per-wave qkw/vt/pl
//     (24.5K total) = 50176 B. ONE barrier in the whole kernel (post x-load).
//   - q-scale and bias folded: prep scales q-rows of W and bias by 1/sqrt(32).
//   - head_gemm: 32-token tiles (bt 25 KB) -> 6 blocks/CU, 24 waves/CU.
// Workspace (~101.3 MB):
//   [0)           ocat bf16 [b][win 1024][n 16][c 384] = 100,663,296 B
//   [+100663296)  w1p bf16 576x192 head-major  (221184 B)
//   [+100884480)  w2p bf16 576x192 head-major  (221184 B)
//   [+101105664)  whb bf16 192x384             (147456 B)
//   [+101253120)  b1p f32 576 head-major scaled (2304 B)
//   [+101255424)  b2p f32 576                   (2304 B)

typedef unsigned short u16;
using bf16x8 = __attribute__((ext_vector_type(8))) short;
using f32x4  = __attribute__((ext_vector_type(4))) float;
using u16x8  = __attribute__((ext_vector_type(8))) unsigned short;
using u16x4  = __attribute__((ext_vector_type(4))) unsigned short;

#define CIN   192
#define NW2   33
#define QSCALE 0.17677669529663687f

__device__ __forceinline__ u16 f2bf(float f) {
    unsigned int x; __builtin_memcpy(&x, &f, 4);
    return (u16)((x + 0x7FFFu + ((x >> 16) & 1u)) >> 16);
}
__device__ __forceinline__ u16x4 pack4(f32x4 v) {
    u16x4 r = {f2bf(v[0]), f2bf(v[1]), f2bf(v[2]), f2bf(v[3])};
    return r;
}
// x-tile LDS column swizzle (unchanged from R2, proven).
__device__ __forceinline__ int xcol(int c, int tok) {
    int blk = (c >> 3) ^ ((tok ^ (tok >> 4)) & 7);
    return blk * 8 + (c & 7);
}

// ---------------------------------------------------------------------------
// prep: head-major permutation co' = h*96 + sec*32 + d  (sec 0=q,1=k,2=v)
//       from co_old = sec*192 + h*32 + d ; q rows/bias scaled by 1/sqrt(32).
// ---------------------------------------------------------------------------
__global__ void prep_conv(const float* __restrict__ w1, const float* __restrict__ w2,
                          const float* __restrict__ wh,
                          const float* __restrict__ b1, const float* __restrict__ b2,
                          u16* __restrict__ w1p, u16* __restrict__ w2p,
                          u16* __restrict__ whb,
                          float* __restrict__ b1p, float* __restrict__ b2p) {
    int i = blockIdx.x * 256 + threadIdx.x;
    if (i < 221184) {
        int j = (i < 110592) ? i : i - 110592;
        int co = j / 192, k = j - co * 192;
        int h = co / 96, r = co - h * 96, sec = r >> 5, d = r & 31;
        int co_old = sec * 192 + h * 32 + d;
        float v = ((i < 110592) ? w1 : w2)[co_old * 192 + k];
        if (sec == 0) v *= QSCALE;
        ((i < 110592) ? w1p : w2p)[j] = f2bf(v);
    } else if (i < 294912) {
        int j = i - 221184;
        whb[j] = f2bf(wh[j]);
    } else if (i < 296064) {
        int j = (i < 295488) ? (i - 294912) : (i - 295488);
        int h = j / 96, r = j - h * 96, sec = r >> 5, d = r & 31;
        float v = ((i < 295488) ? b1 : b2)[sec * 192 + h * 32 + d];
        if (sec == 0) v *= QSCALE;
        ((i < 295488) ? b1p : b2p)[j] = v;
    }
}

// ---------------------------------------------------------------------------
// Fused QKV + attention. 4 windows/block, 384 threads (6 waves = 6 heads).
// Wave w: GEMM co-strip [w*96, +96) (its head's q|k|v), then per-window
// attention entirely wave-private. One __syncthreads (after x load).
// ---------------------------------------------------------------------------
__global__ __launch_bounds__(384, 3) void qkv_attn(const float* __restrict__ x,
                                                   const u16* __restrict__ w1p,
                                                   const float* __restrict__ b1p,
                                                   const u16* __restrict__ w2p,
                                                   const float* __restrict__ b2p,
                                                   u16* __restrict__ ocat) {
    // xl  [0,25600)      : [64 tok][200] u16 (swizzled)
    // qkw [25600,39424)  : [6 waves][16 tok][72] u16  (q d0..31 | k at +32)
    // vt  [39424,45568)  : [6 waves][32 d][16 m] u16
    // pl  [45568,50176)  : [6 waves][16 n][24] u16
    __shared__ __align__(16) char smem[50176];
    u16* xl  = (u16*)smem;
    u16* qkw = (u16*)(smem + 25600);
    u16* vt  = (u16*)(smem + 39424);
    u16* pl  = (u16*)(smem + 45568);

    const int tid  = threadIdx.x;
    const int wave = tid / 64, lane = tid & 63;
    const int lo16 = lane & 15, quad = lane >> 4;

    // XCD-bijective swizzle: 4424 = 8 * 553.
    const int swz = (blockIdx.x & 7) * 553 + (blockIdx.x >> 3);
    const bool br0 = (swz < 2048);

    int b, wy, g;
    const u16* wb; const float* biasp;
    if (br0) {                           // 8 * 32 * 8
        b = swz >> 8; int rem = swz & 255;
        wy = rem >> 3; g = rem & 7;
        wb = w1p; biasp = b1p;
    } else {                             // 8 * 33 * 9
        int bi = swz - 2048;
        b = bi / 297; int rem = bi % 297;
        wy = rem / 9; g = rem % 9;
        wb = w2p; biasp = b2p;
    }
    const int hbase = wy * 4, wbase = g * 16;

    // --- x tile: 4 windows x 16 tok x 192 ch -> LDS bf16 ---
    if (br0) {
#pragma unroll
        for (int it = 0; it < 8; ++it) {
            int i = it * 384 + tid;          // 3072 = c(192) x y(4) x xc(4)
            int c = i >> 4, y = (i >> 2) & 3, xc = i & 3;
            const float4 v = *reinterpret_cast<const float4*>(
                &x[(((size_t)b * CIN + c) * 128 + hbase + y) * 128 + wbase + xc * 4]);
            int t0 = xc * 16 + y * 4;
            xl[(t0 + 0) * 200 + xcol(c, t0 + 0)] = f2bf(v.x);
            xl[(t0 + 1) * 200 + xcol(c, t0 + 1)] = f2bf(v.y);
            xl[(t0 + 2) * 200 + xcol(c, t0 + 2)] = f2bf(v.z);
            xl[(t0 + 3) * 200 + xcol(c, t0 + 3)] = f2bf(v.w);
        }
    } else {
#pragma unroll
        for (int it = 0; it < 8; ++it) {
            int i = it * 384 + tid;
            int c = i >> 4, y = (i >> 2) & 3, xc = i & 3;
            float e0, e1, e2, e3;
            int h = hbase + y - 2;
            int w0 = wbase + xc * 4 - 2;
            bool hok = (unsigned)h < 128u;
            const float* row = &x[(((size_t)b * CIN + c) * 128 + h) * 128];
            if (hok && w0 >= 0 && w0 + 3 < 128) {
                float2 p0 = *reinterpret_cast<const float2*>(&row[w0]);
                float2 p1 = *reinterpret_cast<const float2*>(&row[w0 + 2]);
                e0 = p0.x; e1 = p0.y; e2 = p1.x; e3 = p1.y;
            } else {
                e0 = (hok && w0 >= 0 && w0 < 128)         ? row[w0]     : 0.f;
                e1 = (hok && w0+1 >= 0 && w0+1 < 128)     ? row[w0 + 1] : 0.f;
                e2 = (hok && w0+2 >= 0 && w0+2 < 128)     ? row[w0 + 2] : 0.f;
                e3 = (hok && w0+3 >= 0 && w0+3 < 128)     ? row[w0 + 3] : 0.f;
            }
            int t0 = xc * 16 + y * 4;
            xl[(t0 + 0) * 200 + xcol(c, t0 + 0)] = f2bf(e0);
            xl[(t0 + 1) * 200 + xcol(c, t0 + 1)] = f2bf(e1);
            xl[(t0 + 2) * 200 + xcol(c, t0 + 2)] = f2bf(e2);
            xl[(t0 + 3) * 200 + xcol(c, t0 + 3)] = f2bf(e3);
        }
    }
    __syncthreads();        // the ONLY barrier

    // --- QKV GEMM: wave strip co' = wave*96 (head-major), K=192 in 6 chunks ---
    f32x4 acc[6][4];
#pragma unroll
    for (int mt = 0; mt < 6; ++mt)
#pragma unroll
        for (int nt = 0; nt < 4; ++nt) acc[mt][nt] = f32x4{0.f, 0.f, 0.f, 0.f};

    const u16* wrow = wb + (size_t)(wave * 96 + lo16) * 192 + quad * 8;
#pragma unroll
    for (int s = 0; s < 6; ++s) {
        bf16x8 bfr[4];
#pragma unroll
        for (int nt = 0; nt < 4; ++nt) {
            int tok = nt * 16 + lo16;
            int kb = s * 4 + quad;
            bfr[nt] = *reinterpret_cast<const bf16x8*>(
                &xl[tok * 200 + (((kb ^ ((tok ^ (tok >> 4)) & 7)) << 3))]);
        }
#pragma unroll
        for (int mt = 0; mt < 6; ++mt) {
            bf16x8 afr = *reinterpret_cast<const bf16x8*>(&wrow[mt * 3072 + s * 32]);
#pragma unroll
            for (int nt = 0; nt < 4; ++nt)
                acc[mt][nt] = __builtin_amdgcn_mfma_f32_16x16x32_bf16(afr, bfr[nt], acc[mt][nt], 0, 0, 0);
        }
    }

    // --- bias add (q-part already scaled at prep) ---
#pragma unroll
    for (int mt = 0; mt < 6; ++mt) {
        const float4 bv = *reinterpret_cast<const float4*>(&biasp[wave * 96 + mt * 16 + quad * 4]);
#pragma unroll
        for (int nt = 0; nt < 4; ++nt) {
            acc[mt][nt][0] += bv.x; acc[mt][nt][1] += bv.y;
            acc[mt][nt][2] += bv.z; acc[mt][nt][3] += bv.w;
        }
    }

    // --- attention: wave-private, one window (nt) at a time ---
    u16* qrow = qkw + wave * 1152 + lo16 * 72;   // this token's q|k channels
    u16* vbs  = vt  + wave * 512;                // [32 d][16 m]
    u16* plb  = pl  + wave * 384;                // [16 n][24]
    const bf16x8 z8 = {};
    const f32x4 zc = {0.f, 0.f, 0.f, 0.f};

#pragma unroll
    for (int nt = 0; nt < 4; ++nt) {
        // store mapping for token n = lo16 of window nt
        bool dov; size_t dst = 0;
        if (br0) {
            int wg = wy * 32 + g * 4 + nt;
            dst = (((size_t)(b * 1024 + wg)) * 16 + lo16) * 384;
            dov = true;
        } else {
            int wx = g * 4 + nt;
            int h = wy * 4 + (lo16 >> 2) - 2;
            int w = wx * 4 + (lo16 & 3) - 2;
            dov = (wx < NW2) && (unsigned)h < 128u && (unsigned)w < 128u;
            if (dov) {
                int wg = (h >> 2) * 32 + (w >> 2);
                int nn = (h & 3) * 4 + (w & 3);
                dst = (((size_t)(b * 1024 + wg)) * 16 + nn) * 384 + 192;
            }
        }
        // stage Q,K token-major (d = mt*16 + quad*4 + i; k at ch 32..63)
        *reinterpret_cast<u16x4*>(&qrow[     quad * 4]) = pack4(acc[0][nt]);
        *reinterpret_cast<u16x4*>(&qrow[16 + quad * 4]) = pack4(acc[1][nt]);
        *reinterpret_cast<u16x4*>(&qrow[32 + quad * 4]) = pack4(acc[2][nt]);
        *reinterpret_cast<u16x4*>(&qrow[48 + quad * 4]) = pack4(acc[3][nt]);
        // stage V transposed: vt[d][m]
#pragma unroll
        for (int ht = 0; ht < 2; ++ht)
#pragma unroll
            for (int j = 0; j < 4; ++j)
                vbs[(ht * 16 + quad * 4 + j) * 16 + lo16] = f2bf(acc[4 + ht][nt][j]);

        bf16x8 kfr = *reinterpret_cast<const bf16x8*>(&qrow[32 + quad * 8]);
        bf16x8 qfr = *reinterpret_cast<const bf16x8*>(&qrow[quad * 8]);
        f32x4 st = __builtin_amdgcn_mfma_f32_16x16x32_bf16(kfr, qfr, zc, 0, 0, 0);
        // softmax over m (st[i] = S[m=quad*4+i][n=lo16])
        float mx = fmaxf(fmaxf(st[0], st[1]), fmaxf(st[2], st[3]));
        mx = fmaxf(mx, __shfl_xor(mx, 16));
        mx = fmaxf(mx, __shfl_xor(mx, 32));
        float p0 = __expf(st[0] - mx), p1 = __expf(st[1] - mx);
        float p2 = __expf(st[2] - mx), p3 = __expf(st[3] - mx);
        float sum = p0 + p1 + p2 + p3;
        sum += __shfl_xor(sum, 16);
        sum += __shfl_xor(sum, 32);
        float inv = 1.0f / sum;
        u16x4 pk = {f2bf(p0), f2bf(p1), f2bf(p2), f2bf(p3)};
        *reinterpret_cast<u16x4*>(&plb[lo16 * 24 + quad * 4]) = pk;
        bf16x8 pf = (quad < 2)
            ? *reinterpret_cast<const bf16x8*>(&plb[lo16 * 24 + quad * 8]) : z8;
#pragma unroll
        for (int half = 0; half < 2; ++half) {
            bf16x8 av = (quad < 2)
                ? *reinterpret_cast<const bf16x8*>(&vbs[(half * 16 + lo16) * 16 + quad * 8]) : z8;
            f32x4 o = __builtin_amdgcn_mfma_f32_16x16x32_bf16(av, pf, zc, 0, 0, 0);
            if (dov) {
                u16x4 ok = {f2bf(o[0] * inv), f2bf(o[1] * inv),
                            f2bf(o[2] * inv), f2bf(o[3] * inv)};
                *reinterpret_cast<u16x4*>(&ocat[dst + wave * 32 + half * 16 + quad * 4]) = ok;
            }
        }
    }
}

// ---------------------------------------------------------------------------
// head GEMM: out[b][co 192][h][w] = w_head(192x384) @ o_cat rows + bias.
// 32-token tiles: bt 25 KB -> 6 blocks/CU (24 waves/CU). A direct from global.
// ---------------------------------------------------------------------------
__global__ __launch_bounds__(256, 6) void head_gemm(const u16* __restrict__ ocat,
                                                    const u16* __restrict__ whb,
                                                    const float* __restrict__ bh,
                                                    float* __restrict__ out) {
    __shared__ __align__(16) u16 bt[32 * 392];
    const int tid = threadIdx.x;
    const int wave = tid >> 6, lane = tid & 63;
    const int lo16 = lane & 15, quad = lane >> 4;

    // 8 * 32 * 16 = 4096 blocks; XCD-bijective swizzle (4096 = 8*512)
    int bi = (blockIdx.x & 7) * 512 + (blockIdx.x >> 3);
    int b = bi >> 9; int rem = bi & 511;
    int wy = rem >> 4, g = rem & 15;
    const int wg0 = wy * 32 + g * 2;
    const size_t gbase = ((size_t)(b * 1024 + wg0) * 16) * 384;

#pragma unroll
    for (int it = 0; it < 6; ++it) {       // 1536 chunks of 8 u16, contiguous
        int i = it * 256 + tid;
        u16x8 v = *reinterpret_cast<const u16x8*>(&ocat[gbase + (size_t)i * 8]);
        int row = i / 48, kc = i - row * 48;
        *reinterpret_cast<u16x8*>(&bt[row * 392 + kc * 8]) = v;
    }
    __syncthreads();

    const int co_base = wave * 48;
    f32x4 acc[3][2];
#pragma unroll
    for (int mt = 0; mt < 3; ++mt)
#pragma unroll
        for (int nt = 0; nt < 2; ++nt) acc[mt][nt] = f32x4{0.f, 0.f, 0.f, 0.f};

#pragma unroll
    for (int s = 0; s < 12; ++s) {
        int k0 = s * 32;
        bf16x8 a[3], bb[2];
#pragma unroll
        for (int nt = 0; nt < 2; ++nt)
            bb[nt] = *reinterpret_cast<const bf16x8*>(&bt[(nt * 16 + lo16) * 392 + k0 + quad * 8]);
#pragma unroll
        for (int mt = 0; mt < 3; ++mt)
            a[mt] = *reinterpret_cast<const bf16x8*>(
                &whb[(size_t)(co_base + mt * 16 + lo16) * 384 + k0 + quad * 8]);
#pragma unroll
        for (int mt = 0; mt < 3; ++mt)
#pragma unroll
            for (int nt = 0; nt < 2; ++nt)
                acc[mt][nt] = __builtin_amdgcn_mfma_f32_16x16x32_bf16(a[mt], bb[nt], acc[mt][nt], 0, 0, 0);
    }

    int h = wy * 4 + (lo16 >> 2);
#pragma unroll
    for (int mt = 0; mt < 3; ++mt) {
        int co0 = co_base + mt * 16 + quad * 4;
        const float4 bv = *reinterpret_cast<const float4*>(&bh[co0]);
#pragma unroll
        for (int r = 0; r < 4; ++r) {
            float bias = (r == 0) ? bv.x : (r == 1) ? bv.y : (r == 2) ? bv.z : bv.w;
#pragma unroll
            for (int nt = 0; nt < 2; ++nt) {
                int w = (g * 2 + nt) * 4 + (lo16 & 3);
                out[(((size_t)b * CIN + co0 + r) * 128 + h) * 128 + w] = acc[mt][nt][r] + bias;
            }
        }
    }
}

// ---------------------------------------------------------------------------
extern "C" void kernel_launch(void* const* d_in, const int* in_sizes, int n_in,
                              void* d_out, int out_size, void* d_ws, size_t ws_size,
                              hipStream_t stream) {
    const float* x  = (const float*)d_in[0];
    const float* w1 = (const float*)d_in[1];
    const float* b1 = (const float*)d_in[2];
    const float* w2 = (const float*)d_in[3];
    const float* b2 = (const float*)d_in[4];
    const float* wh = (const float*)d_in[5];
    const float* bh = (const float*)d_in[6];
    float* out = (float*)d_out;

    char* ws = (char*)d_ws;
    u16*   ocat = (u16*)ws;
    u16*   w1p  = (u16*)(ws + 100663296);
    u16*   w2p  = (u16*)(ws + 100884480);
    u16*   whb  = (u16*)(ws + 101105664);
    float* b1p  = (float*)(ws + 101253120);
    float* b2p  = (float*)(ws + 101255424);

    prep_conv<<<1157, 256, 0, stream>>>(w1, w2, wh, b1, b2, w1p, w2p, whb, b1p, b2p);
    qkv_attn<<<4424, 384, 0, stream>>>(x, w1p, b1p, w2p, b2p, ocat);
    head_gemm<<<4096, 256, 0, stream>>>(ocat, whb, bh, out);
}

// Round 6
// 495.046 us; speedup vs baseline: 1.2285x; 1.0848x over previous
//
#include <hip/hip_runtime.h>

// OverlapWindowMHA2d on MI355X (gfx950) — R7.
// R6 retry with ws_size guard: R6's bench died in-container; prime suspect is
// workspace overflow (R6 needed 154.8 MB vs the proven 101.25 MB envelope).
// Two compiled paths, chosen at launch from ws_size:
//   FULL  (ws >= 154.8 MB): prep_w ; prep_x (x -> padded channel-last bf16) ;
//         qkv_attn_g (B-fragments direct from global, ONE barrier) ; head_gemm.
//   FALLBACK (else): prep_w ; qkv_attn_fb (R2-proven structure, x staged via
//         LDS from fp32) ; head_gemm. Fits the original 101,253,120 B layout.
// Both paths: W q-rows pre-scaled by 1/sqrt(32) in prep_w; bias q-part scaled
// in-kernel from the raw fp32 bias pointer (no bias tensors in workspace).
//
// FULL workspace layout (154,779,648 B):
//   [0)           ocat bf16 [b][win 1024][n 16][c 384] = 100,663,296 B
//   [+100663296)  w1b bf16 576x192 (q rows pre-scaled)   (221184 B)
//   [+100884480)  w2b bf16 576x192 (q rows pre-scaled)   (221184 B)
//   [+101105664)  whb bf16 192x384                       (147456 B)
//   [+101253120)  xp  bf16 [8][132][132][192]         (53,526,528 B)
// FALLBACK layout = first four entries only (101,253,120 B).

typedef unsigned short u16;
using bf16x8 = __attribute__((ext_vector_type(8))) short;
using f32x4  = __attribute__((ext_vector_type(4))) float;
using u16x8  = __attribute__((ext_vector_type(8))) unsigned short;
using u16x4  = __attribute__((ext_vector_type(4))) unsigned short;

#define CIN   192
#define NW2   33
#define QSCALE 0.17677669529663687f

__device__ __forceinline__ u16 f2bf(float f) {
    unsigned int x; __builtin_memcpy(&x, &f, 4);
    return (u16)((x + 0x7FFFu + ((x >> 16) & 1u)) >> 16);
}
// x-tile LDS column swizzle (proven in R2): spreads banks for scalar writes,
// keeps 8-elem (16B) k-blocks contiguous for b128 reads.
__device__ __forceinline__ int xcol(int c, int tok) {
    int blk = (c >> 3) ^ ((tok ^ (tok >> 4)) & 7);
    return blk * 8 + (c & 7);
}

// ---------------------------------------------------------------------------
// prep_w: weights -> bf16; q rows (co<192) pre-scaled by 1/sqrt(32).
// ---------------------------------------------------------------------------
__global__ void prep_w(const float* __restrict__ w1, const float* __restrict__ w2,
                       const float* __restrict__ wh,
                       u16* __restrict__ w1b, u16* __restrict__ w2b,
                       u16* __restrict__ whb) {
    int i = blockIdx.x * 256 + threadIdx.x;            // 294912 total
    if (i < 221184) {
        int j = (i < 110592) ? i : i - 110592;
        int co = j / 192;
        float v = ((i < 110592) ? w1 : w2)[j];
        if (co < 192) v *= QSCALE;
        ((i < 110592) ? w1b : w2b)[j] = f2bf(v);
    } else if (i < 294912) {
        int j = i - 221184;
        whb[j] = f2bf(wh[j]);
    }
}

// ---------------------------------------------------------------------------
// prep_x (FULL path): x fp32 [b][c][128][128] -> xp bf16 [b][132][132][c]
// (pad=2 zero halo). One block per (b, hp) row; LDS transpose tile.
// ---------------------------------------------------------------------------
__global__ __launch_bounds__(256, 2) void prep_x(const float* __restrict__ x,
                                                 u16* __restrict__ xp) {
    __shared__ __align__(16) u16 lt[128 * 200];        // 51.2 KB
    int bi = blockIdx.x;                               // 8 * 132 = 1056
    int b = bi / 132, hp = bi % 132;
    u16* orow = xp + ((size_t)(b * 132 + hp)) * 132 * 192;
    const int tid = threadIdx.x;

    if (hp >= 2 && hp < 130) {
        const int h = hp - 2;
        const float* xr = x + (size_t)b * 192 * 128 * 128 + (size_t)h * 128;
#pragma unroll
        for (int it = 0; it < 24; ++it) {
            int i = it * 256 + tid;                    // 6144 = c(192) x wq(32)
            int c = i >> 5, w0 = (i & 31) * 4;
            float4 v = *reinterpret_cast<const float4*>(&xr[(size_t)c * 16384 + w0]);
            lt[(w0 + 0) * 200 + xcol(c, w0 + 0)] = f2bf(v.x);
            lt[(w0 + 1) * 200 + xcol(c, w0 + 1)] = f2bf(v.y);
            lt[(w0 + 2) * 200 + xcol(c, w0 + 2)] = f2bf(v.z);
            lt[(w0 + 3) * 200 + xcol(c, w0 + 3)] = f2bf(v.w);
        }
        __syncthreads();
#pragma unroll
        for (int it = 0; it < 13; ++it) {              // 132 wp x 24 kc = 3168
            int i = it * 256 + tid;
            if (i < 3168) {
                int wp = i / 24, kc = i - wp * 24;
                u16x8 val = {};
                if (wp >= 2 && wp < 130) {
                    int w = wp - 2;
                    int blk = kc ^ ((w ^ (w >> 4)) & 7);
                    val = *reinterpret_cast<const u16x8*>(&lt[w * 200 + blk * 8]);
                }
                *reinterpret_cast<u16x8*>(&orow[(size_t)wp * 192 + kc * 8]) = val;
            }
        }
    } else {
#pragma unroll
        for (int it = 0; it < 13; ++it) {              // zero halo row
            int i = it * 256 + tid;
            if (i < 3168) {
                u16x8 z = {};
                *reinterpret_cast<u16x8*>(&orow[(size_t)i * 8]) = z;
            }
        }
    }
}

// ---------------------------------------------------------------------------
// Shared attention tail (restage -> barrier -> per-wave attention).
// acc layout: acc[9][4] over co strip wave*144, windows nt, bias raw fp32
// (q part scaled in here). Identical math to the R1/R2-proven kernels.
// ---------------------------------------------------------------------------
__device__ __forceinline__ void attn_tail(f32x4 (&acc)[9][4],
                                          const float* __restrict__ bias,
                                          u16* qk, u16* vt, u16* pl,
                                          int wave, int lane, int lo16, int quad,
                                          bool br0, int b, int wy, int g,
                                          u16* __restrict__ ocat) {
#pragma unroll
    for (int mt = 0; mt < 9; ++mt) {
        int co0 = wave * 144 + mt * 16 + quad * 4;
        float4 bv = *reinterpret_cast<const float4*>(&bias[co0]);
        if (co0 < 192) { bv.x *= QSCALE; bv.y *= QSCALE; bv.z *= QSCALE; bv.w *= QSCALE; }
#pragma unroll
        for (int nt = 0; nt < 4; ++nt) {
            int tok = nt * 16 + lo16;
            float v0 = acc[mt][nt][0] + bv.x, v1 = acc[mt][nt][1] + bv.y;
            float v2 = acc[mt][nt][2] + bv.z, v3 = acc[mt][nt][3] + bv.w;
            if (co0 < 384) {
                u16x4 pk = {f2bf(v0), f2bf(v1), f2bf(v2), f2bf(v3)};
                *reinterpret_cast<u16x4*>(&qk[tok * 392 + co0]) = pk;
            } else {
                int dh = co0 - 384;
                int head = dh >> 5, d0 = dh & 31;
                int win = tok >> 4, m = tok & 15;
                u16* vrow = &vt[((win * 6 + head) * 32 + d0) * 16 + m];
                vrow[0]  = f2bf(v0);
                vrow[16] = f2bf(v1);
                vrow[32] = f2bf(v2);
                vrow[48] = f2bf(v3);
            }
        }
    }
    __syncthreads();

    const int win = wave;
    const u16* qbase = qk + (size_t)(win * 16) * 392;
    const bf16x8 z8 = {};
    const f32x4 zc = {0.f, 0.f, 0.f, 0.f};
    bool dov; size_t dst = 0;
    if (br0) {
        int wg = wy * 32 + g * 4 + win;
        dst = (((size_t)(b * 1024 + wg)) * 16 + lo16) * 384;
        dov = true;
    } else {
        int wx = g * 4 + win;
        int h = wy * 4 + (lo16 >> 2) - 2;
        int w = wx * 4 + (lo16 & 3) - 2;
        dov = (wx < NW2) && (unsigned)h < 128u && (unsigned)w < 128u;
        if (dov) {
            int wg = (h >> 2) * 32 + (w >> 2);
            int nn = (h & 3) * 4 + (w & 3);
            dst = (((size_t)(b * 1024 + wg)) * 16 + nn) * 384 + 192;
        }
    }
#pragma unroll
    for (int head = 0; head < 6; ++head) {
        bf16x8 kfr = *reinterpret_cast<const bf16x8*>(
            &qbase[lo16 * 392 + 192 + head * 32 + quad * 8]);
        bf16x8 qfr = *reinterpret_cast<const bf16x8*>(
            &qbase[lo16 * 392 + head * 32 + quad * 8]);
        f32x4 st = __builtin_amdgcn_mfma_f32_16x16x32_bf16(kfr, qfr, zc, 0, 0, 0);
        float mx = fmaxf(fmaxf(st[0], st[1]), fmaxf(st[2], st[3]));
        mx = fmaxf(mx, __shfl_xor(mx, 16));
        mx = fmaxf(mx, __shfl_xor(mx, 32));
        float p0 = __expf(st[0] - mx), p1 = __expf(st[1] - mx);
        float p2 = __expf(st[2] - mx), p3 = __expf(st[3] - mx);
        float sum = p0 + p1 + p2 + p3;
        sum += __shfl_xor(sum, 16);
        sum += __shfl_xor(sum, 32);
        float inv = 1.0f / sum;
        u16x4 pk = {f2bf(p0), f2bf(p1), f2bf(p2), f2bf(p3)};
        *reinterpret_cast<u16x4*>(&pl[(wave * 16 + lo16) * 24 + quad * 4]) = pk;
        bf16x8 pf = (quad < 2)
            ? *reinterpret_cast<const bf16x8*>(&pl[(wave * 16 + lo16) * 24 + quad * 8]) : z8;
        const u16* vbase = &vt[(win * 6 + head) * 32 * 16];
#pragma unroll
        for (int half = 0; half < 2; ++half) {
            bf16x8 av = (quad < 2)
                ? *reinterpret_cast<const bf16x8*>(&vbase[(half * 16 + lo16) * 16 + quad * 8]) : z8;
            f32x4 o = __builtin_amdgcn_mfma_f32_16x16x32_bf16(av, pf, zc, 0, 0, 0);
            if (dov) {
                u16x4 ok = {f2bf(o[0] * inv), f2bf(o[1] * inv),
                            f2bf(o[2] * inv), f2bf(o[3] * inv)};
                *reinterpret_cast<u16x4*>(&ocat[dst + head * 32 + half * 16 + quad * 4]) = ok;
            }
        }
    }
}

// ---------------------------------------------------------------------------
// FULL-path qkv_attn: B-fragments direct from xp (global). ONE barrier.
// ---------------------------------------------------------------------------
__global__ __launch_bounds__(256, 2) void qkv_attn_g(const u16* __restrict__ xp,
                                                     const u16* __restrict__ w1b,
                                                     const float* __restrict__ b1,
                                                     const u16* __restrict__ w2b,
                                                     const float* __restrict__ b2,
                                                     u16* __restrict__ ocat) {
    __shared__ __align__(16) char smem[77824];
    u16* qk = (u16*)smem;
    u16* vt = (u16*)(smem + 50176);
    u16* pl = (u16*)(smem + 74752);

    const int tid  = threadIdx.x;
    const int wave = tid >> 6, lane = tid & 63;
    const int lo16 = lane & 15, quad = lane >> 4;

    const int swz = (blockIdx.x & 7) * 553 + (blockIdx.x >> 3);  // 4424 = 8*553
    const bool br0 = (swz < 2048);

    int b, wy, g;
    const u16* wb; const float* bias;
    if (br0) { b = swz >> 8; int rem = swz & 255; wy = rem >> 3; g = rem & 7;
               wb = w1b; bias = b1; }
    else     { int bi = swz - 2048; b = bi / 297; int rem = bi % 297;
               wy = rem / 9; g = rem % 9; wb = w2b; bias = b2; }

    const int d  = br0 ? 2 : 0;
    const int ty = lo16 >> 2, tx = lo16 & 3;
    const u16* bp[4];
#pragma unroll
    for (int nt = 0; nt < 4; ++nt) {
        int wx = g * 4 + nt;
        if (!br0 && wx > 32) wx = 32;    // OOB windows: valid memory, discarded
        int hp = d + wy * 4 + ty;
        int wp = d + wx * 4 + tx;
        bp[nt] = xp + (((size_t)b * 132 + hp) * 132 + wp) * 192 + quad * 8;
    }

    f32x4 acc[9][4];
#pragma unroll
    for (int mt = 0; mt < 9; ++mt)
#pragma unroll
        for (int nt = 0; nt < 4; ++nt) acc[mt][nt] = f32x4{0.f, 0.f, 0.f, 0.f};

    const u16* wrow = wb + (size_t)(wave * 144 + lo16) * 192 + quad * 8;
#pragma unroll
    for (int s = 0; s < 6; ++s) {
        bf16x8 bfr[4];
#pragma unroll
        for (int nt = 0; nt < 4; ++nt)
            bfr[nt] = *reinterpret_cast<const bf16x8*>(bp[nt] + s * 32);
#pragma unroll
        for (int mt = 0; mt < 9; ++mt) {
            bf16x8 afr = *reinterpret_cast<const bf16x8*>(&wrow[mt * 3072 + s * 32]);
#pragma unroll
            for (int nt = 0; nt < 4; ++nt)
                acc[mt][nt] = __builtin_amdgcn_mfma_f32_16x16x32_bf16(afr, bfr[nt], acc[mt][nt], 0, 0, 0);
        }
    }
    attn_tail(acc, bias, qk, vt, pl, wave, lane, lo16, quad, br0, b, wy, g, ocat);
}

// ---------------------------------------------------------------------------
// FALLBACK qkv_attn: R2-proven structure (x staged fp32->bf16 via LDS).
// ---------------------------------------------------------------------------
__global__ __launch_bounds__(256, 2) void qkv_attn_fb(const float* __restrict__ x,
                                                      const u16* __restrict__ w1b,
                                                      const float* __restrict__ b1,
                                                      const u16* __restrict__ w2b,
                                                      const float* __restrict__ b2,
                                                      u16* __restrict__ ocat) {
    __shared__ __align__(16) char smem[77824];
    u16* xl = (u16*)smem;
    u16* qk = (u16*)smem;
    u16* vt = (u16*)(smem + 50176);
    u16* pl = (u16*)(smem + 74752);

    const int tid  = threadIdx.x;
    const int wave = tid >> 6, lane = tid & 63;
    const int lo16 = lane & 15, quad = lane >> 4;

    const int swz = (blockIdx.x & 7) * 553 + (blockIdx.x >> 3);
    const bool br0 = (swz < 2048);

    int b, wy, g;
    const u16* wb; const float* bias;
    if (br0) { b = swz >> 8; int rem = swz & 255; wy = rem >> 3; g = rem & 7;
               wb = w1b; bias = b1; }
    else     { int bi = swz - 2048; b = bi / 297; int rem = bi % 297;
               wy = rem / 9; g = rem % 9; wb = w2b; bias = b2; }
    const int hbase = wy * 4, wbase = g * 16;

    if (br0) {
#pragma unroll
        for (int it = 0; it < 12; ++it) {
            int i = it * 256 + tid;
            int c = i >> 4, y = (i >> 2) & 3, xc = i & 3;
            const float4 v = *reinterpret_cast<const float4*>(
                &x[(((size_t)b * CIN + c) * 128 + hbase + y) * 128 + wbase + xc * 4]);
            int t0 = xc * 16 + y * 4;
            xl[(t0 + 0) * 200 + xcol(c, t0 + 0)] = f2bf(v.x);
            xl[(t0 + 1) * 200 + xcol(c, t0 + 1)] = f2bf(v.y);
            xl[(t0 + 2) * 200 + xcol(c, t0 + 2)] = f2bf(v.z);
            xl[(t0 + 3) * 200 + xcol(c, t0 + 3)] = f2bf(v.w);
        }
    } else {
#pragma unroll
        for (int it = 0; it < 12; ++it) {
            int i = it * 256 + tid;
            int c = i >> 4, y = (i >> 2) & 3, xc = i & 3;
            float e0, e1, e2, e3;
            int h = hbase + y - 2;
            int w0 = wbase + xc * 4 - 2;
            bool hok = (unsigned)h < 128u;
            const float* row = &x[(((size_t)b * CIN + c) * 128 + h) * 128];
            if (hok && w0 >= 0 && w0 + 3 < 128) {
                float2 p0 = *reinterpret_cast<const float2*>(&row[w0]);
                float2 p1 = *reinterpret_cast<const float2*>(&row[w0 + 2]);
                e0 = p0.x; e1 = p0.y; e2 = p1.x; e3 = p1.y;
            } else {
                e0 = (hok && w0 >= 0 && w0 < 128)         ? row[w0]     : 0.f;
                e1 = (hok && w0+1 >= 0 && w0+1 < 128)     ? row[w0 + 1] : 0.f;
                e2 = (hok && w0+2 >= 0 && w0+2 < 128)     ? row[w0 + 2] : 0.f;
                e3 = (hok && w0+3 >= 0 && w0+3 < 128)     ? row[w0 + 3] : 0.f;
            }
            int t0 = xc * 16 + y * 4;
            xl[(t0 + 0) * 200 + xcol(c, t0 + 0)] = f2bf(e0);
            xl[(t0 + 1) * 200 + xcol(c, t0 + 1)] = f2bf(e1);
            xl[(t0 + 2) * 200 + xcol(c, t0 + 2)] = f2bf(e2);
            xl[(t0 + 3) * 200 + xcol(c, t0 + 3)] = f2bf(e3);
        }
    }
    __syncthreads();

    f32x4 acc[9][4];
#pragma unroll
    for (int mt = 0; mt < 9; ++mt)
#pragma unroll
        for (int nt = 0; nt < 4; ++nt) acc[mt][nt] = f32x4{0.f, 0.f, 0.f, 0.f};

    const u16* wrow = wb + (size_t)(wave * 144 + lo16) * 192 + quad * 8;
#pragma unroll
    for (int s = 0; s < 6; ++s) {
        bf16x8 bfr[4];
#pragma unroll
        for (int nt = 0; nt < 4; ++nt) {
            int tok = nt * 16 + lo16;
            int kb = s * 4 + quad;
            bfr[nt] = *reinterpret_cast<const bf16x8*>(
                &xl[tok * 200 + (((kb ^ ((tok ^ (tok >> 4)) & 7)) << 3))]);
        }
#pragma unroll
        for (int mt = 0; mt < 9; ++mt) {
            bf16x8 afr = *reinterpret_cast<const bf16x8*>(&wrow[mt * 3072 + s * 32]);
#pragma unroll
            for (int nt = 0; nt < 4; ++nt)
                acc[mt][nt] = __builtin_amdgcn_mfma_f32_16x16x32_bf16(afr, bfr[nt], acc[mt][nt], 0, 0, 0);
        }
    }
    __syncthreads();     // xl reads done before qk overwrite
    attn_tail(acc, bias, qk, vt, pl, wave, lane, lo16, quad, br0, b, wy, g, ocat);
}

// ---------------------------------------------------------------------------
// head GEMM: out[b][co 192][h][w] = w_head(192x384) @ o_cat rows + bias.
// 32-token tiles (bt 25 KB) -> high occupancy. Proven in R5.
// ---------------------------------------------------------------------------
__global__ __launch_bounds__(256, 6) void head_gemm(const u16* __restrict__ ocat,
                                                    const u16* __restrict__ whb,
                                                    const float* __restrict__ bh,
                                                    float* __restrict__ out) {
    __shared__ __align__(16) u16 bt[32 * 392];
    const int tid = threadIdx.x;
    const int wave = tid >> 6, lane = tid & 63;
    const int lo16 = lane & 15, quad = lane >> 4;

    int bi = (blockIdx.x & 7) * 512 + (blockIdx.x >> 3);   // 4096 = 8*512
    int b = bi >> 9; int rem = bi & 511;
    int wy = rem >> 4, g = rem & 15;
    const int wg0 = wy * 32 + g * 2;
    const size_t gbase = ((size_t)(b * 1024 + wg0) * 16) * 384;

#pragma unroll
    for (int it = 0; it < 6; ++it) {
        int i = it * 256 + tid;
        u16x8 v = *reinterpret_cast<const u16x8*>(&ocat[gbase + (size_t)i * 8]);
        int row = i / 48, kc = i - row * 48;
        *reinterpret_cast<u16x8*>(&bt[row * 392 + kc * 8]) = v;
    }
    __syncthreads();

    const int co_base = wave * 48;
    f32x4 acc[3][2];
#pragma unroll
    for (int mt = 0; mt < 3; ++mt)
#pragma unroll
        for (int nt = 0; nt < 2; ++nt) acc[mt][nt] = f32x4{0.f, 0.f, 0.f, 0.f};

#pragma unroll
    for (int s = 0; s < 12; ++s) {
        int k0 = s * 32;
        bf16x8 a[3], bb[2];
#pragma unroll
        for (int nt = 0; nt < 2; ++nt)
            bb[nt] = *reinterpret_cast<const bf16x8*>(&bt[(nt * 16 + lo16) * 392 + k0 + quad * 8]);
#pragma unroll
        for (int mt = 0; mt < 3; ++mt)
            a[mt] = *reinterpret_cast<const bf16x8*>(
                &whb[(size_t)(co_base + mt * 16 + lo16) * 384 + k0 + quad * 8]);
#pragma unroll
        for (int mt = 0; mt < 3; ++mt)
#pragma unroll
            for (int nt = 0; nt < 2; ++nt)
                acc[mt][nt] = __builtin_amdgcn_mfma_f32_16x16x32_bf16(a[mt], bb[nt], acc[mt][nt], 0, 0, 0);
    }

    int h = wy * 4 + (lo16 >> 2);
#pragma unroll
    for (int mt = 0; mt < 3; ++mt) {
        int co0 = co_base + mt * 16 + quad * 4;
        const float4 bv = *reinterpret_cast<const float4*>(&bh[co0]);
#pragma unroll
        for (int r = 0; r < 4; ++r) {
            float bias = (r == 0) ? bv.x : (r == 1) ? bv.y : (r == 2) ? bv.z : bv.w;
#pragma unroll
            for (int nt = 0; nt < 2; ++nt) {
                int w = (g * 2 + nt) * 4 + (lo16 & 3);
                out[(((size_t)b * CIN + co0 + r) * 128 + h) * 128 + w] = acc[mt][nt][r] + bias;
            }
        }
    }
}

// ---------------------------------------------------------------------------
extern "C" void kernel_launch(void* const* d_in, const int* in_sizes, int n_in,
                              void* d_out, int out_size, void* d_ws, size_t ws_size,
                              hipStream_t stream) {
    const float* x  = (const float*)d_in[0];
    const float* w1 = (const float*)d_in[1];
    const float* b1 = (const float*)d_in[2];
    const float* w2 = (const float*)d_in[3];
    const float* b2 = (const float*)d_in[4];
    const float* wh = (const float*)d_in[5];
    const float* bh = (const float*)d_in[6];
    float* out = (float*)d_out;

    char* ws = (char*)d_ws;
    u16* ocat = (u16*)ws;
    u16* w1b  = (u16*)(ws + 100663296);
    u16* w2b  = (u16*)(ws + 100884480);
    u16* whb  = (u16*)(ws + 101105664);
    u16* xp   = (u16*)(ws + 101253120);

    const size_t need_full = 101253120u + 53526528u;   // 154,779,648 B

    prep_w<<<1152, 256, 0, stream>>>(w1, w2, wh, w1b, w2b, whb);
    if (ws_size >= need_full) {
        prep_x<<<1056, 256, 0, stream>>>(x, xp);
        qkv_attn_g<<<4424, 256, 0, stream>>>(xp, w1b, b1, w2b, b2, ocat);
    } else {
        qkv_attn_fb<<<4424, 256, 0, stream>>>(x, w1b, b1, w2b, b2, ocat);
    }
    head_gemm<<<4096, 256, 0, stream>>>(ocat, whb, bh, out);
}